// Round 19
// baseline (215.058 us; speedup 1.0000x reference)
//
#include <hip/hip_runtime.h>
#include <hip/hip_bf16.h>
#include <math.h>

// ---------------- sizes ----------------
#define BATCH 128
#define SEQ   2048
#define FIN   128
#define DD    16
#define NLAYERS 6
#define SST   20              // in-LDS site row stride (floats) for tail
#define SWEEPS 6

// ws layout (floats)
#define BUFA_F  (BATCH*SEQ*DD)            // 4,194,304
#define BUFB_F  (BATCH*(SEQ/2)*DD)        // 2,097,152
#define COEF_OFF (BUFA_F + BUFB_F)        // per-layer [UC 8192 | WT 4096]
#define ENT_OFF  (COEF_OFF + NLAYERS*12288)

// ---------------- front: blocks 0..5 = prep; blocks 6.. = embed (R13/R18-exact) ----------------
__global__ __launch_bounds__(128) void k_front(const float* __restrict__ seq,
                                               const float* __restrict__ W,
                                               const float* __restrict__ bias,
                                               const float* __restrict__ u,
                                               const float* __restrict__ w,
                                               float* __restrict__ coef,
                                               float* __restrict__ out) {
    __shared__ float sW[2048];
    __shared__ float sR[64*132];
    int t = threadIdx.x;
    if (blockIdx.x < 6) {
        int l = blockIdx.x;
        for (int ij = t; ij < 256; ij += 128) {
            const float* ub = u + (size_t)l*65536 + (size_t)ij*256;   // [k][l2]
            float a1[16], a2[16];
#pragma unroll
            for (int k = 0; k < 16; ++k) { a1[k] = 0.0f; a2[k] = 0.0f; }
#pragma unroll
            for (int k = 0; k < 16; ++k) {
#pragma unroll
                for (int z = 0; z < 16; ++z) {
                    float v = ub[k*16 + z];
                    a1[k] += v;
                    a2[z] += v;
                }
            }
            float* ucb = coef + (size_t)l*12288 + ij*32;
#pragma unroll
            for (int k = 0; k < 16; ++k) {
                ucb[k]      = a1[k]*(1.0f/16.0f);
                ucb[16 + k] = a2[k]*(1.0f/16.0f);
            }
            const float* wb = w + (size_t)l*4096;                  // [a][i][j]
            float* wtb = coef + (size_t)l*12288 + 8192 + ij*16;    // [ij][a]
#pragma unroll
            for (int a = 0; a < 16; ++a) wtb[a] = wb[a*256 + ij];
        }
        return;
    }
    // ---- embed: 2 tiles x 64 rows; thread: outputs 4q..4q+3, rows {g, g+32} ----
    size_t rowbase = (size_t)(blockIdx.x - 6) * 128;
    {
        const float4* W4 = (const float4*)W;
        float4* s4 = (float4*)sW;
#pragma unroll
        for (int it = 0; it < 4; ++it) s4[it*128 + t] = W4[it*128 + t];
    }
    int q = t & 3, g = t >> 2;           // outputs 4q..4q+3; rows g, g+32
    float4 bv = *(const float4*)(bias + q*4);
    const float4* sR4 = (const float4*)sR;
    const float4* sW4 = (const float4*)sW;

#pragma unroll 1
    for (int ps = 0; ps < 2; ++ps) {
        {
            const float4* seq4 = (const float4*)seq + (rowbase + ps*64)*32;
#pragma unroll
            for (int it = 0; it < 16; ++it) {
                int idx = it*128 + t;
                *(float4*)&sR[(idx >> 5)*132 + (idx & 31)*4] = seq4[idx];
            }
        }
        __syncthreads();
        float a0[4] = { bv.x, bv.y, bv.z, bv.w };
        float a1[4] = { bv.x, bv.y, bv.z, bv.w };
#pragma unroll 4
        for (int kk = 0; kk < 32; ++kk) {
            float4 r0 = sR4[g*33 + kk];
            float4 r1 = sR4[(g + 32)*33 + kk];
            float rc0[4] = { r0.x, r0.y, r0.z, r0.w };
            float rc1[4] = { r1.x, r1.y, r1.z, r1.w };
#pragma unroll
            for (int c = 0; c < 4; ++c) {
                float4 wv = sW4[(kk*4 + c)*4 + q];
                a0[0] = fmaf(rc0[c], wv.x, a0[0]);
                a0[1] = fmaf(rc0[c], wv.y, a0[1]);
                a0[2] = fmaf(rc0[c], wv.z, a0[2]);
                a0[3] = fmaf(rc0[c], wv.w, a0[3]);
                a1[0] = fmaf(rc1[c], wv.x, a1[0]);
                a1[1] = fmaf(rc1[c], wv.y, a1[1]);
                a1[2] = fmaf(rc1[c], wv.z, a1[2]);
                a1[3] = fmaf(rc1[c], wv.w, a1[3]);
            }
        }
        float p0 = 0.0f, p1 = 0.0f;
#pragma unroll
        for (int j = 0; j < 4; ++j) { p0 = fmaf(a0[j], a0[j], p0); p1 = fmaf(a1[j], a1[j], p1); }
        p0 += __shfl_xor(p0, 1); p0 += __shfl_xor(p0, 2);
        p1 += __shfl_xor(p1, 1); p1 += __shfl_xor(p1, 2);
        float inv0 = 1.0f / fmaxf(sqrtf(p0), 1e-12f);
        float inv1 = 1.0f / fmaxf(sqrtf(p1), 1e-12f);
        size_t r0w = rowbase + ps*64 + g;
        *(float4*)(out + r0w*16 + q*4)        = make_float4(a0[0]*inv0, a0[1]*inv0, a0[2]*inv0, a0[3]*inv0);
        *(float4*)(out + (r0w + 32)*16 + q*4) = make_float4(a1[0]*inv1, a1[1]*inv1, a1[2]*inv1, a1[3]*inv1);
        __syncthreads();
    }
}

// ---------------- one MERA layer: og-decomposition, 2 pairs/thread (R13-exact) ----------------
__global__ __launch_bounds__(256) void k_layer(const float* __restrict__ in,
                                               float* __restrict__ outp,
                                               const float* __restrict__ coefl) {
    __shared__ float cbuf[8192];
    __shared__ float spl[64*36];
    int t = threadIdx.x;
    int og = t & 7, pg = t >> 3;
    int lane = t & 63, base = lane & ~7;

    const float4* wtf = (const float4*)(coefl + 8192);
    float4 wr0 = wtf[0*256 + t];
    float4 wr1 = wtf[1*256 + t];
    float4 wr2 = wtf[2*256 + t];
    float4 wr3 = wtf[3*256 + t];

    {
        const float4* ucf = (const float4*)coefl;
        float4* c4 = (float4*)cbuf;
#pragma unroll
        for (int it = 0; it < 8; ++it) c4[it*256 + t] = ucf[it*256 + t];
    }
    {
        const float4* ing = (const float4*)in + (size_t)blockIdx.x*512;
        float4 v0 = ing[t];
        float4 v1 = ing[t + 256];
        *(float4*)&spl[(t >> 3)*36 + (t & 7)*4]        = v0;
        *(float4*)&spl[((t >> 3) + 32)*36 + (t & 7)*4] = v1;
    }
    __syncthreads();

    float s1v[2][16];
#pragma unroll
    for (int pp = 0; pp < 2; ++pp) {
        int p = pg + pp*32;
#pragma unroll
        for (int g = 0; g < 4; ++g) {
            float4 v = *(const float4*)&spl[p*36 + 16 + g*4];
            s1v[pp][g*4+0]=v.x; s1v[pp][g*4+1]=v.y; s1v[pp][g*4+2]=v.z; s1v[pp][g*4+3]=v.w;
        }
    }

    float accv[2][4];
    accv[0][0]=0.f; accv[0][1]=0.f; accv[0][2]=0.f; accv[0][3]=0.f;
    accv[1][0]=0.f; accv[1][1]=0.f; accv[1][2]=0.f; accv[1][3]=0.f;

    for (int i = 0; i < 16; ++i) {
        float s0a = spl[pg*36 + i];
        float s0b = spl[(pg + 32)*36 + i];
        const float4* uc = (const float4*)&cbuf[i*512] + og;
#pragma unroll
        for (int j = 0; j < 16; ++j) {
            float4 cv = uc[j*8];
            float pa = s0a * s1v[0][j];
            float pb = s0b * s1v[1][j];
            accv[0][0] = fmaf(pa, cv.x, accv[0][0]);
            accv[0][1] = fmaf(pa, cv.y, accv[0][1]);
            accv[0][2] = fmaf(pa, cv.z, accv[0][2]);
            accv[0][3] = fmaf(pa, cv.w, accv[0][3]);
            accv[1][0] = fmaf(pb, cv.x, accv[1][0]);
            accv[1][1] = fmaf(pb, cv.y, accv[1][1]);
            accv[1][2] = fmaf(pb, cv.z, accv[1][2]);
            accv[1][3] = fmaf(pb, cv.w, accv[1][3]);
        }
    }
    __syncthreads();
    {
        float4* c4 = (float4*)cbuf;
        c4[0*256 + t] = wr0;
        c4[1*256 + t] = wr1;
        c4[2*256 + t] = wr2;
        c4[3*256 + t] = wr3;
    }
    __syncthreads();

    float o2f[2][16];
#pragma unroll
    for (int j = 0; j < 16; ++j) {
        int src = base + 4 + (j >> 2);
        o2f[0][j] = __shfl(accv[0][j & 3], src, 64);
        o2f[1][j] = __shfl(accv[1][j & 3], src, 64);
    }

    float r0a = 0.f, r1a = 0.f, r0b = 0.f, r1b = 0.f;
    for (int grp = 0; grp < 4; ++grp) {
#pragma unroll
        for (int c = 0; c < 4; ++c) {
            float o1a = __shfl(accv[0][c], base + grp, 64);
            float o1b = __shfl(accv[1][c], base + grp, 64);
            const float2* wrow = (const float2*)&cbuf[(grp*4 + c)*256] + og;
#pragma unroll
            for (int j = 0; j < 16; ++j) {
                float2 wv = wrow[j*8];
                float qa = o1a * o2f[0][j];
                float qb = o1b * o2f[1][j];
                r0a = fmaf(qa, wv.x, r0a);
                r1a = fmaf(qa, wv.y, r1a);
                r0b = fmaf(qb, wv.x, r0b);
                r1b = fmaf(qb, wv.y, r1b);
            }
        }
    }

    size_t gp = (size_t)blockIdx.x*64;
    *(float2*)&outp[(gp + pg)*16 + og*2]      = make_float2(r0a, r1a);
    *(float2*)&outp[(gp + pg + 32)*16 + og*2] = make_float2(r0b, r1b);
}

// ---------------- in-LDS layer body with row offsets (verified R5/R7/R8 math) ----------------
// reads sL rows rbase+2p, rbase+2p+1; writes sL row wbase+p (p = pg+pp*32).
template<int P, bool LAST>
__device__ __forceinline__ void layer_body(float* sL, const float* coef,
                                           float* outp, int npg, int t, int bid,
                                           int rbase, int wbase) {
    int og = t & 7, pg = t >> 3;
    int lane = t & 63, base = lane & ~7;
    bool act = pg < npg;

    float accv[P][4];
    float s1v[P][16];
#pragma unroll
    for (int pp = 0; pp < P; ++pp) { accv[pp][0]=0.f; accv[pp][1]=0.f; accv[pp][2]=0.f; accv[pp][3]=0.f; }

    if (act) {
#pragma unroll
        for (int pp = 0; pp < P; ++pp) {
            int r = rbase + 2*(pg + pp*32) + 1;
#pragma unroll
            for (int g = 0; g < 4; ++g) {
                float4 v = *(const float4*)&sL[r*SST + g*4];
                s1v[pp][g*4+0]=v.x; s1v[pp][g*4+1]=v.y; s1v[pp][g*4+2]=v.z; s1v[pp][g*4+3]=v.w;
            }
        }
        for (int i = 0; i < 16; ++i) {
            float s0[P];
#pragma unroll
            for (int pp = 0; pp < P; ++pp) s0[pp] = sL[(rbase + 2*(pg + pp*32))*SST + i];
            const float4* uc = (const float4*)&coef[i*512] + og;
#pragma unroll
            for (int j = 0; j < 16; ++j) {
                float4 cv = uc[j*8];
#pragma unroll
                for (int pp = 0; pp < P; ++pp) {
                    float p = s0[pp] * s1v[pp][j];
                    accv[pp][0] = fmaf(p, cv.x, accv[pp][0]);
                    accv[pp][1] = fmaf(p, cv.y, accv[pp][1]);
                    accv[pp][2] = fmaf(p, cv.z, accv[pp][2]);
                    accv[pp][3] = fmaf(p, cv.w, accv[pp][3]);
                }
            }
        }
    }
    __syncthreads();

    if (act) {
        float o2f[P][16];
#pragma unroll
        for (int j = 0; j < 16; ++j) {
            int src = base + 4 + (j >> 2);
#pragma unroll
            for (int pp = 0; pp < P; ++pp)
                o2f[pp][j] = __shfl(accv[pp][j & 3], src, 64);
        }
        float r0[P], r1[P];
#pragma unroll
        for (int pp = 0; pp < P; ++pp) { r0[pp] = 0.f; r1[pp] = 0.f; }
        for (int grp = 0; grp < 4; ++grp) {
#pragma unroll
            for (int c = 0; c < 4; ++c) {
                float o1i[P];
#pragma unroll
                for (int pp = 0; pp < P; ++pp)
                    o1i[pp] = __shfl(accv[pp][c], base + grp, 64);
#pragma unroll
                for (int j = 0; j < 16; ++j) {
                    float2 wv = *(const float2*)&coef[8192 + ((grp*4+c)*16 + j)*16 + og*2];
#pragma unroll
                    for (int pp = 0; pp < P; ++pp) {
                        float q = o1i[pp] * o2f[pp][j];
                        r0[pp] = fmaf(q, wv.x, r0[pp]);
                        r1[pp] = fmaf(q, wv.y, r1[pp]);
                    }
                }
            }
        }
        if (LAST) {
#pragma unroll
            for (int pp = 0; pp < P; ++pp) {
                int p = pg + pp*32;
                *(float2*)&outp[((size_t)bid*32 + p)*16 + og*2] = make_float2(r0[pp], r1[pp]);
            }
        } else {
#pragma unroll
            for (int pp = 0; pp < P; ++pp) {
                int p = pg + pp*32;
                *(float2*)&sL[(wbase + p)*SST + og*2] = make_float2(r0[pp], r1[pp]);
            }
        }
    }
    __syncthreads();
}

// ---------------- tail: layers 2,3,4,5 fused; block = 1 batch (512 rows in, 32 out) ----------
__global__ __launch_bounds__(256) void k_tail(const float* __restrict__ in,
                                              const float* __restrict__ coefg,
                                              float* __restrict__ outp) {
    __shared__ float coef[12288];
    __shared__ float sL[512*SST];      // 40 KB; total ~90 KB (<=160 KB/CU, 1 block/CU)
    int t = threadIdx.x, bid = blockIdx.x;

    // stage 512 rows (2048 float4)
    const float4* in4 = (const float4*)in + (size_t)bid*2048;
#pragma unroll
    for (int it = 0; it < 8; ++it) {
        int f = it*256 + t;
        *(float4*)&sL[(f >> 2)*SST + (f & 3)*4] = in4[f];
    }
#pragma unroll 1
    for (int l = 0; l < 4; ++l) {
        const float4* src = (const float4*)(coefg + (size_t)(2 + l)*12288);
        __syncthreads();
        for (int x = t; x < 3072; x += 256) ((float4*)coef)[x] = src[x];
        __syncthreads();
        switch (l) {
            case 0:     // L2: 256 pairs in two halves
                layer_body<4,false>(sL, coef, outp, 32, t, bid, 0,   0);
                layer_body<4,false>(sL, coef, outp, 32, t, bid, 256, 128);
                break;
            case 1: layer_body<4,false>(sL, coef, outp, 32, t, bid, 0, 0); break;  // L3
            case 2: layer_body<2,false>(sL, coef, outp, 32, t, bid, 0, 0); break;  // L4
            case 3: layer_body<1,true >(sL, coef, outp, 32, t, bid, 0, 0); break;  // L5
        }
    }
}

// ---------------- phi_q part 1: per-matrix Jacobi, 384 independent blocks ----------------
__device__ __forceinline__ void rot_cs(float al, float be, float ga, float& c, float& s) {
    float ze = (be - al) / (2.0f * ga);
    float tt = copysignf(1.0f, ze) / (fabsf(ze) + sqrtf(1.0f + ze*ze));
    c = 1.0f / sqrtf(1.0f + tt*tt);
    s = c * tt;
}

__global__ __launch_bounds__(64) void k_phi(const float* __restrict__ sites,
                                            float* __restrict__ ent) {
    __shared__ float S[512];
    __shared__ float C[256];
    __shared__ float sv[16];
    int bid = blockIdx.x;
    int role = bid >> 7;
    int b = bid & 127;
    int t = threadIdx.x;
    const float* sp = sites + (size_t)b*512;

    if (role == 0) {
        for (int x = t; x < 512; x += 64) S[x] = sp[x];
        __syncthreads();
        for (int e = t; e < 256; e += 64) {
            int i = e & 15, j = e >> 4;
            float a = 0.0f;
            for (int k = 0; k < 16; ++k) a = fmaf(S[i*16+k], S[(16+j)*16+k], a);
            C[j*16 + i] = a;
        }
        __syncthreads();
        for (int sw = 0; sw < SWEEPS; ++sw) {
            for (int r = 0; r < 15; ++r) {
                int pr = t >> 3, sub = t & 7;
                int p, q;
                if (pr == 0) { p = 15; q = r; }
                else { p = (r + pr) % 15; q = (r + 15 - pr) % 15; }
                float u0 = C[p*16 + 2*sub],   u1v = C[p*16 + 2*sub + 1];
                float v0 = C[q*16 + 2*sub],   v1v = C[q*16 + 2*sub + 1];
                float al = u0*u0 + u1v*u1v;
                float be = v0*v0 + v1v*v1v;
                float ga = u0*v0 + u1v*v1v;
                al += __shfl_xor(al,1); al += __shfl_xor(al,2); al += __shfl_xor(al,4);
                be += __shfl_xor(be,1); be += __shfl_xor(be,2); be += __shfl_xor(be,4);
                ga += __shfl_xor(ga,1); ga += __shfl_xor(ga,2); ga += __shfl_xor(ga,4);
                if (ga != 0.0f) {
                    float c, s; rot_cs(al, be, ga, c, s);
                    C[p*16 + 2*sub]     = fmaf(c, u0, -s*v0);
                    C[p*16 + 2*sub + 1] = fmaf(c, u1v, -s*v1v);
                    C[q*16 + 2*sub]     = fmaf(s, u0,  c*v0);
                    C[q*16 + 2*sub + 1] = fmaf(s, u1v, c*v1v);
                }
                __syncthreads();
            }
        }
        if (t < 16) {
            float s2 = 0.0f;
            for (int rr = 0; rr < 16; ++rr) { float v = C[t*16+rr]; s2 = fmaf(v, v, s2); }
            sv[t] = sqrtf(s2);
        }
        __syncthreads();
        if (t == 0) {
            float sum = 0.0f;
            for (int i2 = 0; i2 < 16; ++i2) sum += sv[i2];
            float den = sum + 1e-8f;
            float e2 = 0.0f;
            for (int i2 = 0; i2 < 16; ++i2) {
                float sn = sv[i2] / den;
                e2 -= sn * logf(sn + 1e-8f);
            }
            ent[b] = e2;
        }
    } else {
        int ro = (role == 1) ? 0 : 256;
        for (int x = t; x < 256; x += 64) S[x] = sp[ro + x];
        __syncthreads();
        if (t < 64) {
            int i = t & 7, j = t >> 3;
            float a = 0.0f;
            for (int k = 0; k < 16; ++k) a = fmaf(S[i*16+k], S[(8+j)*16+k], a);
            C[j*8 + i] = a;
        }
        __syncthreads();
        for (int sw = 0; sw < SWEEPS; ++sw) {
            for (int r = 0; r < 7; ++r) {
                if (t < 32) {
                    int pr = t >> 3, sub = t & 7;
                    int p, q;
                    if (pr == 0) { p = 7; q = r; }
                    else { p = (r + pr) % 7; q = (r + 7 - pr) % 7; }
                    float uu = C[p*8 + sub], vv = C[q*8 + sub];
                    float al = uu*uu, be = vv*vv, ga = uu*vv;
                    al += __shfl_xor(al,1); al += __shfl_xor(al,2); al += __shfl_xor(al,4);
                    be += __shfl_xor(be,1); be += __shfl_xor(be,2); be += __shfl_xor(be,4);
                    ga += __shfl_xor(ga,1); ga += __shfl_xor(ga,2); ga += __shfl_xor(ga,4);
                    if (ga != 0.0f) {
                        float c, s; rot_cs(al, be, ga, c, s);
                        C[p*8 + sub] = fmaf(c, uu, -s*vv);
                        C[q*8 + sub] = fmaf(s, uu,  c*vv);
                    }
                }
                __syncthreads();
            }
        }
        if (t < 8) {
            float s2 = 0.0f;
            for (int rr = 0; rr < 8; ++rr) { float v = C[t*8+rr]; s2 = fmaf(v, v, s2); }
            sv[t] = sqrtf(s2);
        }
        __syncthreads();
        if (t == 0) {
            float sum = 0.0f;
            for (int i2 = 0; i2 < 8; ++i2) sum += sv[i2];
            float den = sum + 1e-8f;
            float e2 = 0.0f;
            for (int i2 = 0; i2 < 8; ++i2) {
                float sn = sv[i2] / den;
                e2 -= sn * logf(sn + 1e-8f);
            }
            ent[role*128 + b] = e2;
        }
    }
}

__global__ __launch_bounds__(128) void k_phi2(const float* __restrict__ ent,
                                              float* __restrict__ phi) {
    int b = threadIdx.x;
    phi[b] = fmaxf(ent[b] - (ent[128 + b] + ent[256 + b]), 0.0f);
}

// ---------------- launcher ----------------
extern "C" void kernel_launch(void* const* d_in, const int* in_sizes, int n_in,
                              void* d_out, int out_size, void* d_ws, size_t ws_size,
                              hipStream_t stream) {
    const float* seq  = (const float*)d_in[0];
    const float* W    = (const float*)d_in[1];
    const float* bias = (const float*)d_in[2];
    const float* u    = (const float*)d_in[3];
    const float* w    = (const float*)d_in[4];
    float* out = (float*)d_out;
    float* ws  = (float*)d_ws;

    float* bufA  = ws;
    float* bufB  = ws + BUFA_F;
    float* coefw = ws + COEF_OFF;
    float* entb  = ws + ENT_OFF;

    // prep (blocks 0..5) + embed (blocks 6..2053, 128 rows each, 128 threads)
    k_front<<<6 + (BATCH*SEQ)/128, 128, 0, stream>>>(seq, W, bias, u, w, coefw, bufA);

    // layers 0..1, then fused tail 2..5
    k_layer<<<2048, 256, 0, stream>>>(bufA, bufB, coefw + 0*12288);
    k_layer<<<1024, 256, 0, stream>>>(bufB, bufA, coefw + 1*12288);
    k_tail <<< 128, 256, 0, stream>>>(bufA, coefw, out);

    k_phi <<<3*BATCH, 64, 0, stream>>>(out, entb);
    k_phi2<<<1, 128, 0, stream>>>(entb, out + BATCH*32*DD);
}

// Round 20
// 200.522 us; speedup vs baseline: 1.0725x; 1.0725x over previous
//
#include <hip/hip_runtime.h>
#include <hip/hip_bf16.h>
#include <math.h>

// ---------------- sizes ----------------
#define BATCH 128
#define SEQ   2048
#define FIN   128
#define DD    16
#define NLAYERS 6
#define SST   20              // in-LDS site row stride (floats) for tail
#define SWEEPS 6

// ws layout (floats)
#define BUFA_F  (BATCH*SEQ*DD)            // 4,194,304
#define BUFB_F  (BATCH*(SEQ/2)*DD)        // 2,097,152
#define COEF_OFF (BUFA_F + BUFB_F)        // per-layer [UC 8192 | WT 4096]
#define ENT_OFF  (COEF_OFF + NLAYERS*12288)

// ---------------- front: blocks 0..5 = prep; blocks 6.. = embed (R13-exact) ----------------
__global__ __launch_bounds__(128) void k_front(const float* __restrict__ seq,
                                               const float* __restrict__ W,
                                               const float* __restrict__ bias,
                                               const float* __restrict__ u,
                                               const float* __restrict__ w,
                                               float* __restrict__ coef,
                                               float* __restrict__ out) {
    __shared__ float sW[2048];
    __shared__ float sR[64*132];
    int t = threadIdx.x;
    if (blockIdx.x < 6) {
        int l = blockIdx.x;
        for (int ij = t; ij < 256; ij += 128) {
            const float* ub = u + (size_t)l*65536 + (size_t)ij*256;   // [k][l2]
            float a1[16], a2[16];
#pragma unroll
            for (int k = 0; k < 16; ++k) { a1[k] = 0.0f; a2[k] = 0.0f; }
#pragma unroll
            for (int k = 0; k < 16; ++k) {
#pragma unroll
                for (int z = 0; z < 16; ++z) {
                    float v = ub[k*16 + z];
                    a1[k] += v;
                    a2[z] += v;
                }
            }
            float* ucb = coef + (size_t)l*12288 + ij*32;
#pragma unroll
            for (int k = 0; k < 16; ++k) {
                ucb[k]      = a1[k]*(1.0f/16.0f);
                ucb[16 + k] = a2[k]*(1.0f/16.0f);
            }
            const float* wb = w + (size_t)l*4096;                  // [a][i][j]
            float* wtb = coef + (size_t)l*12288 + 8192 + ij*16;    // [ij][a]
#pragma unroll
            for (int a = 0; a < 16; ++a) wtb[a] = wb[a*256 + ij];
        }
        return;
    }
    // ---- embed: 2 tiles x 64 rows; thread: outputs 4q..4q+3, rows {g, g+32} ----
    size_t rowbase = (size_t)(blockIdx.x - 6) * 128;
    {
        const float4* W4 = (const float4*)W;
        float4* s4 = (float4*)sW;
#pragma unroll
        for (int it = 0; it < 4; ++it) s4[it*128 + t] = W4[it*128 + t];
    }
    int q = t & 3, g = t >> 2;           // outputs 4q..4q+3; rows g, g+32
    float4 bv = *(const float4*)(bias + q*4);
    const float4* sR4 = (const float4*)sR;
    const float4* sW4 = (const float4*)sW;

#pragma unroll 1
    for (int ps = 0; ps < 2; ++ps) {
        {
            const float4* seq4 = (const float4*)seq + (rowbase + ps*64)*32;
#pragma unroll
            for (int it = 0; it < 16; ++it) {
                int idx = it*128 + t;
                *(float4*)&sR[(idx >> 5)*132 + (idx & 31)*4] = seq4[idx];
            }
        }
        __syncthreads();
        float a0[4] = { bv.x, bv.y, bv.z, bv.w };
        float a1[4] = { bv.x, bv.y, bv.z, bv.w };
#pragma unroll 4
        for (int kk = 0; kk < 32; ++kk) {
            float4 r0 = sR4[g*33 + kk];
            float4 r1 = sR4[(g + 32)*33 + kk];
            float rc0[4] = { r0.x, r0.y, r0.z, r0.w };
            float rc1[4] = { r1.x, r1.y, r1.z, r1.w };
#pragma unroll
            for (int c = 0; c < 4; ++c) {
                float4 wv = sW4[(kk*4 + c)*4 + q];
                a0[0] = fmaf(rc0[c], wv.x, a0[0]);
                a0[1] = fmaf(rc0[c], wv.y, a0[1]);
                a0[2] = fmaf(rc0[c], wv.z, a0[2]);
                a0[3] = fmaf(rc0[c], wv.w, a0[3]);
                a1[0] = fmaf(rc1[c], wv.x, a1[0]);
                a1[1] = fmaf(rc1[c], wv.y, a1[1]);
                a1[2] = fmaf(rc1[c], wv.z, a1[2]);
                a1[3] = fmaf(rc1[c], wv.w, a1[3]);
            }
        }
        float p0 = 0.0f, p1 = 0.0f;
#pragma unroll
        for (int j = 0; j < 4; ++j) { p0 = fmaf(a0[j], a0[j], p0); p1 = fmaf(a1[j], a1[j], p1); }
        p0 += __shfl_xor(p0, 1); p0 += __shfl_xor(p0, 2);
        p1 += __shfl_xor(p1, 1); p1 += __shfl_xor(p1, 2);
        float inv0 = 1.0f / fmaxf(sqrtf(p0), 1e-12f);
        float inv1 = 1.0f / fmaxf(sqrtf(p1), 1e-12f);
        size_t r0w = rowbase + ps*64 + g;
        *(float4*)(out + r0w*16 + q*4)        = make_float4(a0[0]*inv0, a0[1]*inv0, a0[2]*inv0, a0[3]*inv0);
        *(float4*)(out + (r0w + 32)*16 + q*4) = make_float4(a1[0]*inv1, a1[1]*inv1, a1[2]*inv1, a1[3]*inv1);
        __syncthreads();
    }
}

// ---------------- one MERA layer: og-decomposition, 2 pairs/thread (R13-exact) ----------------
__global__ __launch_bounds__(256) void k_layer(const float* __restrict__ in,
                                               float* __restrict__ outp,
                                               const float* __restrict__ coefl) {
    __shared__ float cbuf[8192];
    __shared__ float spl[64*36];
    int t = threadIdx.x;
    int og = t & 7, pg = t >> 3;
    int lane = t & 63, base = lane & ~7;

    const float4* wtf = (const float4*)(coefl + 8192);
    float4 wr0 = wtf[0*256 + t];
    float4 wr1 = wtf[1*256 + t];
    float4 wr2 = wtf[2*256 + t];
    float4 wr3 = wtf[3*256 + t];

    {
        const float4* ucf = (const float4*)coefl;
        float4* c4 = (float4*)cbuf;
#pragma unroll
        for (int it = 0; it < 8; ++it) c4[it*256 + t] = ucf[it*256 + t];
    }
    {
        const float4* ing = (const float4*)in + (size_t)blockIdx.x*512;
        float4 v0 = ing[t];
        float4 v1 = ing[t + 256];
        *(float4*)&spl[(t >> 3)*36 + (t & 7)*4]        = v0;
        *(float4*)&spl[((t >> 3) + 32)*36 + (t & 7)*4] = v1;
    }
    __syncthreads();

    float s1v[2][16];
#pragma unroll
    for (int pp = 0; pp < 2; ++pp) {
        int p = pg + pp*32;
#pragma unroll
        for (int g = 0; g < 4; ++g) {
            float4 v = *(const float4*)&spl[p*36 + 16 + g*4];
            s1v[pp][g*4+0]=v.x; s1v[pp][g*4+1]=v.y; s1v[pp][g*4+2]=v.z; s1v[pp][g*4+3]=v.w;
        }
    }

    float accv[2][4];
    accv[0][0]=0.f; accv[0][1]=0.f; accv[0][2]=0.f; accv[0][3]=0.f;
    accv[1][0]=0.f; accv[1][1]=0.f; accv[1][2]=0.f; accv[1][3]=0.f;

    for (int i = 0; i < 16; ++i) {
        float s0a = spl[pg*36 + i];
        float s0b = spl[(pg + 32)*36 + i];
        const float4* uc = (const float4*)&cbuf[i*512] + og;
#pragma unroll
        for (int j = 0; j < 16; ++j) {
            float4 cv = uc[j*8];
            float pa = s0a * s1v[0][j];
            float pb = s0b * s1v[1][j];
            accv[0][0] = fmaf(pa, cv.x, accv[0][0]);
            accv[0][1] = fmaf(pa, cv.y, accv[0][1]);
            accv[0][2] = fmaf(pa, cv.z, accv[0][2]);
            accv[0][3] = fmaf(pa, cv.w, accv[0][3]);
            accv[1][0] = fmaf(pb, cv.x, accv[1][0]);
            accv[1][1] = fmaf(pb, cv.y, accv[1][1]);
            accv[1][2] = fmaf(pb, cv.z, accv[1][2]);
            accv[1][3] = fmaf(pb, cv.w, accv[1][3]);
        }
    }
    __syncthreads();
    {
        float4* c4 = (float4*)cbuf;
        c4[0*256 + t] = wr0;
        c4[1*256 + t] = wr1;
        c4[2*256 + t] = wr2;
        c4[3*256 + t] = wr3;
    }
    __syncthreads();

    float o2f[2][16];
#pragma unroll
    for (int j = 0; j < 16; ++j) {
        int src = base + 4 + (j >> 2);
        o2f[0][j] = __shfl(accv[0][j & 3], src, 64);
        o2f[1][j] = __shfl(accv[1][j & 3], src, 64);
    }

    float r0a = 0.f, r1a = 0.f, r0b = 0.f, r1b = 0.f;
    for (int grp = 0; grp < 4; ++grp) {
#pragma unroll
        for (int c = 0; c < 4; ++c) {
            float o1a = __shfl(accv[0][c], base + grp, 64);
            float o1b = __shfl(accv[1][c], base + grp, 64);
            const float2* wrow = (const float2*)&cbuf[(grp*4 + c)*256] + og;
#pragma unroll
            for (int j = 0; j < 16; ++j) {
                float2 wv = wrow[j*8];
                float qa = o1a * o2f[0][j];
                float qb = o1b * o2f[1][j];
                r0a = fmaf(qa, wv.x, r0a);
                r1a = fmaf(qa, wv.y, r1a);
                r0b = fmaf(qb, wv.x, r0b);
                r1b = fmaf(qb, wv.y, r1b);
            }
        }
    }

    size_t gp = (size_t)blockIdx.x*64;
    *(float2*)&outp[(gp + pg)*16 + og*2]      = make_float2(r0a, r1a);
    *(float2*)&outp[(gp + pg + 32)*16 + og*2] = make_float2(r0b, r1b);
}

// ---------------- in-LDS layer body (verified R5/R7/R8) ----------------
template<int P, bool LAST>
__device__ __forceinline__ void layer_body(float* sL, const float* coef,
                                           float* outp, int npg, int t, int bid) {
    int og = t & 7, pg = t >> 3;
    int lane = t & 63, base = lane & ~7;
    bool act = pg < npg;

    float accv[P][4];
    float s1v[P][16];
#pragma unroll
    for (int pp = 0; pp < P; ++pp) { accv[pp][0]=0.f; accv[pp][1]=0.f; accv[pp][2]=0.f; accv[pp][3]=0.f; }

    if (act) {
#pragma unroll
        for (int pp = 0; pp < P; ++pp) {
            int r = 2*(pg + pp*32) + 1;
#pragma unroll
            for (int g = 0; g < 4; ++g) {
                float4 v = *(const float4*)&sL[r*SST + g*4];
                s1v[pp][g*4+0]=v.x; s1v[pp][g*4+1]=v.y; s1v[pp][g*4+2]=v.z; s1v[pp][g*4+3]=v.w;
            }
        }
        for (int i = 0; i < 16; ++i) {
            float s0[P];
#pragma unroll
            for (int pp = 0; pp < P; ++pp) s0[pp] = sL[(2*(pg + pp*32))*SST + i];
            const float4* uc = (const float4*)&coef[i*512] + og;
#pragma unroll
            for (int j = 0; j < 16; ++j) {
                float4 cv = uc[j*8];
#pragma unroll
                for (int pp = 0; pp < P; ++pp) {
                    float p = s0[pp] * s1v[pp][j];
                    accv[pp][0] = fmaf(p, cv.x, accv[pp][0]);
                    accv[pp][1] = fmaf(p, cv.y, accv[pp][1]);
                    accv[pp][2] = fmaf(p, cv.z, accv[pp][2]);
                    accv[pp][3] = fmaf(p, cv.w, accv[pp][3]);
                }
            }
        }
    }
    __syncthreads();

    if (act) {
        float o2f[P][16];
#pragma unroll
        for (int j = 0; j < 16; ++j) {
            int src = base + 4 + (j >> 2);
#pragma unroll
            for (int pp = 0; pp < P; ++pp)
                o2f[pp][j] = __shfl(accv[pp][j & 3], src, 64);
        }
        float r0[P], r1[P];
#pragma unroll
        for (int pp = 0; pp < P; ++pp) { r0[pp] = 0.f; r1[pp] = 0.f; }
        for (int grp = 0; grp < 4; ++grp) {
#pragma unroll
            for (int c = 0; c < 4; ++c) {
                float o1i[P];
#pragma unroll
                for (int pp = 0; pp < P; ++pp)
                    o1i[pp] = __shfl(accv[pp][c], base + grp, 64);
#pragma unroll
                for (int j = 0; j < 16; ++j) {
                    float2 wv = *(const float2*)&coef[8192 + ((grp*4+c)*16 + j)*16 + og*2];
#pragma unroll
                    for (int pp = 0; pp < P; ++pp) {
                        float q = o1i[pp] * o2f[pp][j];
                        r0[pp] = fmaf(q, wv.x, r0[pp]);
                        r1[pp] = fmaf(q, wv.y, r1[pp]);
                    }
                }
            }
        }
        if (LAST) {
#pragma unroll
            for (int pp = 0; pp < P; ++pp) {
                int p = pg + pp*32;
                *(float2*)&outp[((size_t)bid*32 + p)*16 + og*2] = make_float2(r0[pp], r1[pp]);
            }
        } else {
#pragma unroll
            for (int pp = 0; pp < P; ++pp) {
                int p = pg + pp*32;
                *(float2*)&sL[p*SST + og*2] = make_float2(r0[pp], r1[pp]);
            }
        }
    }
    __syncthreads();
}

// ---------------- tail: layers 3,4,5 fused; block = 1 batch ----------------
__global__ __launch_bounds__(256) void k_tail(const float* __restrict__ in,
                                              const float* __restrict__ coefg,
                                              float* __restrict__ outp) {
    __shared__ float coef[12288];
    __shared__ float sL[256*SST];
    int t = threadIdx.x, bid = blockIdx.x;

    const float4* in4 = (const float4*)in + (size_t)bid*1024;
#pragma unroll
    for (int it = 0; it < 4; ++it) {
        int f = it*256 + t;
        *(float4*)&sL[(f >> 2)*SST + (f & 3)*4] = in4[f];
    }
#pragma unroll 1
    for (int l = 0; l < 3; ++l) {
        const float4* src = (const float4*)(coefg + (size_t)(3 + l)*12288);
        __syncthreads();
        for (int x = t; x < 3072; x += 256) ((float4*)coef)[x] = src[x];
        __syncthreads();
        switch (l) {
            case 0: layer_body<4,false>(sL, coef, outp, 32, t, bid); break;
            case 1: layer_body<2,false>(sL, coef, outp, 32, t, bid); break;
            case 2: layer_body<1,true >(sL, coef, outp, 32, t, bid); break;
        }
    }
}

// ---------------- phi_q part 1: per-matrix Jacobi, 384 independent blocks ----------------
__device__ __forceinline__ void rot_cs(float al, float be, float ga, float& c, float& s) {
    float ze = (be - al) / (2.0f * ga);
    float tt = copysignf(1.0f, ze) / (fabsf(ze) + sqrtf(1.0f + ze*ze));
    c = 1.0f / sqrtf(1.0f + tt*tt);
    s = c * tt;
}

__global__ __launch_bounds__(64) void k_phi(const float* __restrict__ sites,
                                            float* __restrict__ ent) {
    __shared__ float S[512];
    __shared__ float C[256];
    __shared__ float sv[16];
    int bid = blockIdx.x;
    int role = bid >> 7;
    int b = bid & 127;
    int t = threadIdx.x;
    const float* sp = sites + (size_t)b*512;

    if (role == 0) {
        for (int x = t; x < 512; x += 64) S[x] = sp[x];
        __syncthreads();
        for (int e = t; e < 256; e += 64) {
            int i = e & 15, j = e >> 4;
            float a = 0.0f;
            for (int k = 0; k < 16; ++k) a = fmaf(S[i*16+k], S[(16+j)*16+k], a);
            C[j*16 + i] = a;
        }
        __syncthreads();
        for (int sw = 0; sw < SWEEPS; ++sw) {
            for (int r = 0; r < 15; ++r) {
                int pr = t >> 3, sub = t & 7;
                int p, q;
                if (pr == 0) { p = 15; q = r; }
                else { p = (r + pr) % 15; q = (r + 15 - pr) % 15; }
                float u0 = C[p*16 + 2*sub],   u1v = C[p*16 + 2*sub + 1];
                float v0 = C[q*16 + 2*sub],   v1v = C[q*16 + 2*sub + 1];
                float al = u0*u0 + u1v*u1v;
                float be = v0*v0 + v1v*v1v;
                float ga = u0*v0 + u1v*v1v;
                al += __shfl_xor(al,1); al += __shfl_xor(al,2); al += __shfl_xor(al,4);
                be += __shfl_xor(be,1); be += __shfl_xor(be,2); be += __shfl_xor(be,4);
                ga += __shfl_xor(ga,1); ga += __shfl_xor(ga,2); ga += __shfl_xor(ga,4);
                if (ga != 0.0f) {
                    float c, s; rot_cs(al, be, ga, c, s);
                    C[p*16 + 2*sub]     = fmaf(c, u0, -s*v0);
                    C[p*16 + 2*sub + 1] = fmaf(c, u1v, -s*v1v);
                    C[q*16 + 2*sub]     = fmaf(s, u0,  c*v0);
                    C[q*16 + 2*sub + 1] = fmaf(s, u1v, c*v1v);
                }
                __syncthreads();
            }
        }
        if (t < 16) {
            float s2 = 0.0f;
            for (int rr = 0; rr < 16; ++rr) { float v = C[t*16+rr]; s2 = fmaf(v, v, s2); }
            sv[t] = sqrtf(s2);
        }
        __syncthreads();
        if (t == 0) {
            float sum = 0.0f;
            for (int i2 = 0; i2 < 16; ++i2) sum += sv[i2];
            float den = sum + 1e-8f;
            float e2 = 0.0f;
            for (int i2 = 0; i2 < 16; ++i2) {
                float sn = sv[i2] / den;
                e2 -= sn * logf(sn + 1e-8f);
            }
            ent[b] = e2;
        }
    } else {
        int ro = (role == 1) ? 0 : 256;
        for (int x = t; x < 256; x += 64) S[x] = sp[ro + x];
        __syncthreads();
        if (t < 64) {
            int i = t & 7, j = t >> 3;
            float a = 0.0f;
            for (int k = 0; k < 16; ++k) a = fmaf(S[i*16+k], S[(8+j)*16+k], a);
            C[j*8 + i] = a;
        }
        __syncthreads();
        for (int sw = 0; sw < SWEEPS; ++sw) {
            for (int r = 0; r < 7; ++r) {
                if (t < 32) {
                    int pr = t >> 3, sub = t & 7;
                    int p, q;
                    if (pr == 0) { p = 7; q = r; }
                    else { p = (r + pr) % 7; q = (r + 7 - pr) % 7; }
                    float uu = C[p*8 + sub], vv = C[q*8 + sub];
                    float al = uu*uu, be = vv*vv, ga = uu*vv;
                    al += __shfl_xor(al,1); al += __shfl_xor(al,2); al += __shfl_xor(al,4);
                    be += __shfl_xor(be,1); be += __shfl_xor(be,2); be += __shfl_xor(be,4);
                    ga += __shfl_xor(ga,1); ga += __shfl_xor(ga,2); ga += __shfl_xor(ga,4);
                    if (ga != 0.0f) {
                        float c, s; rot_cs(al, be, ga, c, s);
                        C[p*8 + sub] = fmaf(c, uu, -s*vv);
                        C[q*8 + sub] = fmaf(s, uu,  c*vv);
                    }
                }
                __syncthreads();
            }
        }
        if (t < 8) {
            float s2 = 0.0f;
            for (int rr = 0; rr < 8; ++rr) { float v = C[t*8+rr]; s2 = fmaf(v, v, s2); }
            sv[t] = sqrtf(s2);
        }
        __syncthreads();
        if (t == 0) {
            float sum = 0.0f;
            for (int i2 = 0; i2 < 8; ++i2) sum += sv[i2];
            float den = sum + 1e-8f;
            float e2 = 0.0f;
            for (int i2 = 0; i2 < 8; ++i2) {
                float sn = sv[i2] / den;
                e2 -= sn * logf(sn + 1e-8f);
            }
            ent[role*128 + b] = e2;
        }
    }
}

__global__ __launch_bounds__(128) void k_phi2(const float* __restrict__ ent,
                                              float* __restrict__ phi) {
    int b = threadIdx.x;
    phi[b] = fmaxf(ent[b] - (ent[128 + b] + ent[256 + b]), 0.0f);
}

// ---------------- launcher ----------------
extern "C" void kernel_launch(void* const* d_in, const int* in_sizes, int n_in,
                              void* d_out, int out_size, void* d_ws, size_t ws_size,
                              hipStream_t stream) {
    const float* seq  = (const float*)d_in[0];
    const float* W    = (const float*)d_in[1];
    const float* bias = (const float*)d_in[2];
    const float* u    = (const float*)d_in[3];
    const float* w    = (const float*)d_in[4];
    float* out = (float*)d_out;
    float* ws  = (float*)d_ws;

    float* bufA  = ws;
    float* bufB  = ws + BUFA_F;
    float* coefw = ws + COEF_OFF;
    float* entb  = ws + ENT_OFF;

    // prep (blocks 0..5) + embed (blocks 6..2053, 128 rows each, 128 threads)
    k_front<<<6 + (BATCH*SEQ)/128, 128, 0, stream>>>(seq, W, bias, u, w, coefw, bufA);

    // layers 0..2 (R13-exact P=2, 64 pairs/block), then fused tail 3..5
    k_layer<<<2048, 256, 0, stream>>>(bufA, bufB, coefw + 0*12288);
    k_layer<<<1024, 256, 0, stream>>>(bufB, bufA, coefw + 1*12288);
    k_layer<<< 512, 256, 0, stream>>>(bufA, bufB, coefw + 2*12288);
    k_tail <<< 128, 256, 0, stream>>>(bufB, coefw, out);

    k_phi <<<3*BATCH, 64, 0, stream>>>(out, entb);
    k_phi2<<<1, 128, 0, stream>>>(entb, out + BATCH*32*DD);
}